// Round 11
// baseline (2498.988 us; speedup 1.0000x reference)
//
#include <hip/hip_runtime.h>
#include <hip/hip_bf16.h>
#include <hip/hip_cooperative_groups.h>

typedef __bf16 bf16;
typedef __bf16 bf16x4 __attribute__((ext_vector_type(4)));
typedef __bf16 bf16x8 __attribute__((ext_vector_type(8)));
typedef float f32x4 __attribute__((ext_vector_type(4)));

static __device__ __forceinline__ bf16 f2b(float x) { return (bf16)x; }
static __device__ __forceinline__ float b2f(bf16 x) { return (float)x; }

static __device__ __forceinline__ f32x4 mfma16(bf16x8 a, bf16x8 b, f32x4 c) {
  return __builtin_amdgcn_mfma_f32_16x16x32_bf16(a, b, c, 0, 0, 0);
}

// coherent (cross-XCD) 16B load: bypass L2 via sc0 sc1. Valid only after
// s_waitcnt vmcnt + sched_barrier(0).
static __device__ __forceinline__ bf16x8 loadb8_cc(const bf16* p) {
  bf16x8 v;
  asm volatile("global_load_dwordx4 %0, %1, off sc0 sc1" : "=v"(v) : "v"(p) : "memory");
  return v;
}
// coherent 16B store (write-through to coherence point)
static __device__ __forceinline__ void storeb8_cc(bf16* p, bf16x8 v) {
  asm volatile("global_store_dwordx4 %0, %1, off sc0 sc1" :: "v"(p), "v"(v) : "memory");
}

// ---------------------------------------------------------------------------
// pad_gather_cvt: dst row m = 320 bf16 (cols 300..319 zero) from f32 src row.
// If seq != null: src row = seq[b*400+s] with (s=m/32, b=m%32), else row m.
__global__ __launch_bounds__(256) void pad_gather_cvt(
    const float* __restrict__ src, bf16* __restrict__ dst,
    const int* __restrict__ seq, int nrows) {
  int row = blockIdx.x * 4 + (threadIdx.x >> 6);
  int lane = threadIdx.x & 63;
  if (row >= nrows) return;
  int srow;
  if (seq) {
    int s = row >> 5, b = row & 31;
    srow = seq[b * 400 + s];
  } else {
    srow = row;
  }
  const float* sp = src + (size_t)srow * 300;
  bf16* dp = dst + (size_t)row * 320;
  for (int i = lane; i < 320; i += 64) dp[i] = (i < 300) ? f2b(sp[i]) : (bf16)0.f;
}

// ---------------------------------------------------------------------------
// gemm_bt_al2: C[z][M][N] = A[M][K] * W_z[N][K]^T + bias_z, A f32 (hi/lo
// split -> f32-faithful), W f32 converted to bf16 in-kernel (bit-identical
// to the old pre-conversion), C f32. z = blockIdx.z picks direction.
__global__ __launch_bounds__(256) void gemm_bt_al2(
    const float* __restrict__ A, const float* __restrict__ WF,
    const float* __restrict__ WB, const float* __restrict__ biasF,
    const float* __restrict__ biasB, float* __restrict__ C,
    int M, int N, int K) {
  __shared__ bf16 AsH[128][72];
  __shared__ bf16 AsL[128][72];
  __shared__ bf16 Ws[128][72];
  const int z = blockIdx.z;
  const float* W = z ? WB : WF;
  const float* bias = z ? biasB : biasF;
  float* Cz = C + (size_t)z * M * N;
  const int n0 = blockIdx.x * 128, m0 = blockIdx.y * 128;
  const int tid = threadIdx.x;
  const int wave = tid >> 6, lane = tid & 63;
  const int l15 = lane & 15, lq = lane >> 4;
  const int wm = (wave >> 1) * 64, wn = (wave & 1) * 64;

  f32x4 acc[4][4] = {};

  for (int k0 = 0; k0 < K; k0 += 64) {
    __syncthreads();
#pragma unroll
    for (int i = 0; i < 8; ++i) {      // A: 128x64 f32, hi/lo split
      int c = tid + 256 * i;
      int r = c >> 4, cc = (c & 15) * 4;
      int gr = m0 + r;
      float4 v = {0.f, 0.f, 0.f, 0.f};
      if (gr < M) v = *(const float4*)(A + (size_t)gr * K + k0 + cc);
      float vv[4] = {v.x, v.y, v.z, v.w};
#pragma unroll
      for (int j = 0; j < 4; ++j) {
        bf16 h = f2b(vv[j]);
        AsH[r][cc + j] = h;
        AsL[r][cc + j] = f2b(vv[j] - b2f(h));
      }
    }
#pragma unroll
    for (int i = 0; i < 8; ++i) {      // W: 128x64 f32 -> bf16 hi
      int c = tid + 256 * i;
      int r = c >> 4, cc = (c & 15) * 4;
      float4 v = *(const float4*)(W + (size_t)(n0 + r) * K + k0 + cc);
      Ws[r][cc + 0] = f2b(v.x);
      Ws[r][cc + 1] = f2b(v.y);
      Ws[r][cc + 2] = f2b(v.z);
      Ws[r][cc + 3] = f2b(v.w);
    }
    __syncthreads();
#pragma unroll
    for (int ks = 0; ks < 64; ks += 32) {
      bf16x8 afH[4], afL[4], bfr[4];
#pragma unroll
      for (int i = 0; i < 4; ++i) {
        afH[i] = *(const bf16x8*)&AsH[wm + i * 16 + l15][ks + lq * 8];
        afL[i] = *(const bf16x8*)&AsL[wm + i * 16 + l15][ks + lq * 8];
      }
#pragma unroll
      for (int j = 0; j < 4; ++j)
        bfr[j] = *(const bf16x8*)&Ws[wn + j * 16 + l15][ks + lq * 8];
#pragma unroll
      for (int i = 0; i < 4; ++i)
#pragma unroll
        for (int j = 0; j < 4; ++j) {
          acc[i][j] = mfma16(afH[i], bfr[j], acc[i][j]);
          acc[i][j] = mfma16(afL[i], bfr[j], acc[i][j]);
        }
    }
  }

#pragma unroll
  for (int i = 0; i < 4; ++i)
#pragma unroll
    for (int j = 0; j < 4; ++j) {
      int col = n0 + wn + j * 16 + l15;
      float bv = bias[col];
#pragma unroll
      for (int r = 0; r < 4; ++r) {
        int row = m0 + wm + i * 16 + lq * 4 + r;
        if (row < M) Cz[(size_t)row * N + col] = acc[i][j][r] + bv;
      }
    }
}

// ---------------------------------------------------------------------------
// Word-level GRU, fenceless producer-consumer (round-9 spin/publish), with
// h-loads issued before the x-projection so their LLC latency hides under
// the x MFMAs. 64 blocks x 256 threads: dir=bx>>5, nb=bx&31 owns 16 h-cols.
// kh=wave>>1 splits K, mh=wave&1 picks batch tile; kh==1 reduces + epilogue.
// hexb: [dir][parity][nb][plane(hi/lo)][32 rows][16 cols] bf16.
__global__ __launch_bounds__(256) void gru_word(
    const float* __restrict__ whhF, const float* __restrict__ whhB,
    const float* __restrict__ bhhF, const float* __restrict__ bhhB,
    const float* __restrict__ bihF, const float* __restrict__ bihB,
    const bf16* __restrict__ wpad,   // [2][1536][320] bf16 (padded w_ih)
    const bf16* __restrict__ xpad,   // [400*32][320] bf16 (padded emb gather)
    bf16* __restrict__ hexb,         // [2][2][32][2][32][16] bf16
    unsigned* __restrict__ flags,    // [2][32] u32 (zeroed)
    float* __restrict__ srep)        // [672][1024] f32
{
  __shared__ bf16 WlH[48][516];
  __shared__ bf16 WlL[48][516];
  __shared__ bf16 Xw[48][324];
  __shared__ float red[2][4][64][4];
  __shared__ __align__(16) bf16 stg[2][32][16];  // [plane][row][relcol]
  const int tid = threadIdx.x;
  const int bx = blockIdx.x;
  const int dir = bx >> 5, nb = bx & 31;
  const int c0 = nb * 16;
  const float* whh = dir ? whhB : whhF;
  const float* bhh = dir ? bhhB : bhhF;
  const float* bih = dir ? bihB : bihF;
  const bf16* wih = wpad + (size_t)dir * 1536 * 320;
  unsigned* flg = flags + dir * 32;

  // stage w_hh slice with hi/lo split: LDS row r=g*16+rc <-> w_hh[g*512+c0+rc]
#pragma unroll
  for (int i = 0; i < 24; ++i) {
    int c = tid + 256 * i;
    int r = c >> 7, kc = (c & 127) * 4;
    int gr = ((r >> 4) << 9) + c0 + (r & 15);
    float4 v = *(const float4*)(whh + (size_t)gr * 512 + kc);
    float vv[4] = {v.x, v.y, v.z, v.w};
#pragma unroll
    for (int j = 0; j < 4; ++j) {
      bf16 h = f2b(vv[j]);
      WlH[r][kc + j] = h;
      WlL[r][kc + j] = f2b(vv[j] - b2f(h));
    }
  }
#pragma unroll
  for (int i = 0; i < 8; ++i) {
    int c = tid + 256 * i;
    if (c < 1920) {
      int r = c / 40, ch = (c % 40) * 8;
      int gr = ((r >> 4) << 9) + c0 + (r & 15);
      *(bf16x8*)&Xw[r][ch] = *(const bf16x8*)(wih + (size_t)gr * 320 + ch);
    }
  }
  __syncthreads();

  const int wave = tid >> 6, lane = tid & 63;
  const int kh = wave >> 1;            // K half
  const int mh = wave & 1;             // batch tile
  const int m0 = mh * 16;
  const int l15 = lane & 15, lq = lane >> 4;
  const int colg = c0 + l15;
  const int rowq = m0 + lq * 4;
  const int arow = m0 + l15;           // A-fragment batch row
  const int nboff = lq >> 1;           // chunk-owner offset within 32-K slab
  const int coff = (lq & 1) * 8;       // col offset within chunk row
  const int kb = kh * 160;             // x K-range base for this wave
  const float bhr = bhh[colg];
  const float bhz = bhh[512 + colg];
  const float bhn = bhh[1024 + colg];
  const float bir = bih[colg];
  const float biz = bih[512 + colg];
  const float bin_ = bih[1024 + colg];

  float pacc0 = 0.f, pacc1 = 0.f, pacc2 = 0.f, pacc3 = 0.f;
  float hp_reg[4] = {0.f, 0.f, 0.f, 0.f};   // own h_prev in registers (kh==1)
  bf16* hex_d = hexb + (size_t)dir * 32768 * 2;

  for (int it = 0; it < 400; ++it) {
    const int t = dir ? (399 - it) : it;
    f32x4 accR = {}, accZ = {}, xN = {}, hN = {};

    bf16x8 hiA[8], loA[8];
    if (it > 0) {
      // wait for all 32 producer blocks of this direction at step it-1
      if (tid < 32) {
        while (__hip_atomic_load(&flg[tid], __ATOMIC_RELAXED,
                                 __HIP_MEMORY_SCOPE_AGENT) < (unsigned)it)
          __builtin_amdgcn_s_sleep(1);
      }
      __syncthreads();

      // issue coherent h loads NOW; latency hides under x-projection below.
      // k element = kh*256 + c*32 + lq*8 + j -> owner chunk nb' = k/16 =
      // kh*16 + c*2 + (lq>>1), within-chunk col = (lq&1)*8 + j.
      const bf16* hb = hex_d + (size_t)((it - 1) & 1) * 32768;
      const int inrow = arow * 16 + coff;
#pragma unroll
      for (int c = 0; c < 8; ++c) {
        const bf16* ph = hb + (size_t)(kh * 16 + c * 2 + nboff) * 1024 + inrow;
        hiA[c] = loadb8_cc(ph);
        loA[c] = loadb8_cc(ph + 512);
      }
    }

    // x-projection (overlaps in-flight h loads), K split across kh
    {
      const bf16* xrow = xpad + (size_t)(t * 32 + arow) * 320;
#pragma unroll
      for (int k0 = 0; k0 < 160; k0 += 32) {
        const int kk = kb + k0 + lq * 8;
        bf16x8 a = *(const bf16x8*)(xrow + kk);
        accR = mfma16(a, *(const bf16x8*)&Xw[l15][kk], accR);
        accZ = mfma16(a, *(const bf16x8*)&Xw[16 + l15][kk], accZ);
        xN = mfma16(a, *(const bf16x8*)&Xw[32 + l15][kk], xN);
      }
    }

    if (it > 0) {
      asm volatile("s_waitcnt vmcnt(0)" ::: "memory");
      __builtin_amdgcn_sched_barrier(0);
#pragma unroll
      for (int c = 0; c < 8; ++c) {
        const int kk = kh * 256 + c * 32 + lq * 8;
        bf16x8 wrh = *(const bf16x8*)&WlH[l15][kk];
        bf16x8 wrl = *(const bf16x8*)&WlL[l15][kk];
        bf16x8 wzh = *(const bf16x8*)&WlH[16 + l15][kk];
        bf16x8 wzl = *(const bf16x8*)&WlL[16 + l15][kk];
        bf16x8 wnh = *(const bf16x8*)&WlH[32 + l15][kk];
        bf16x8 wnl = *(const bf16x8*)&WlL[32 + l15][kk];
        accR = mfma16(hiA[c], wrh, accR);
        accR = mfma16(loA[c], wrh, accR);
        accR = mfma16(hiA[c], wrl, accR);
        accZ = mfma16(hiA[c], wzh, accZ);
        accZ = mfma16(loA[c], wzh, accZ);
        accZ = mfma16(hiA[c], wzl, accZ);
        hN = mfma16(hiA[c], wnh, hN);
        hN = mfma16(loA[c], wnh, hN);
        hN = mfma16(hiA[c], wnl, hN);
      }
    }

    // cross-wave K reduction
    if (kh == 0) {
      *(f32x4*)&red[mh][0][lane][0] = accR;
      *(f32x4*)&red[mh][1][lane][0] = accZ;
      *(f32x4*)&red[mh][2][lane][0] = xN;
      *(f32x4*)&red[mh][3][lane][0] = hN;
    }
    __syncthreads();
    if (kh == 1) {
      accR = accR + *(const f32x4*)&red[mh][0][lane][0];
      accZ = accZ + *(const f32x4*)&red[mh][1][lane][0];
      xN = xN + *(const f32x4*)&red[mh][2][lane][0];
      hN = hN + *(const f32x4*)&red[mh][3][lane][0];

      float h2v[4];
#pragma unroll
      for (int r = 0; r < 4; ++r) {
        int b = rowq + r;
        float rr = 1.f / (1.f + expf(-(accR[r] + bir + bhr)));
        float zz = 1.f / (1.f + expf(-(accZ[r] + biz + bhz)));
        float nn = tanhf(xN[r] + bin_ + rr * (hN[r] + bhn));
        h2v[r] = (1.f - zz) * nn + zz * hp_reg[r];
        hp_reg[r] = h2v[r];
        bf16 hi = f2b(h2v[r]);
        stg[0][b][l15] = hi;
        stg[1][b][l15] = f2b(h2v[r] - b2f(hi));
      }

      // segment mean pooling (f32)
      int sg = (t == 0) ? 0 : ((t + 19) / 20);
      if (sg > 20) sg = 20;
      float ic = (sg == 0) ? 1.0f : (sg == 20 ? (1.0f / 19.0f) : 0.05f);
      pacc0 += h2v[0] * ic; pacc1 += h2v[1] * ic;
      pacc2 += h2v[2] * ic; pacc3 += h2v[3] * ic;
      bool flush = dir ? (t == 0 || (t % 20) == 1) : ((t % 20) == 0 || t == 399);
      if (flush) {
        float* sp = srep + ((size_t)(sg * 32 + rowq) * 1024) + (dir << 9) + colg;
        sp[0] = pacc0; sp[1024] = pacc1;
        sp[2048] = pacc2; sp[3072] = pacc3;
        pacc0 = pacc1 = pacc2 = pacc3 = 0.f;
      }
    }

    __syncthreads();   // stg complete
    // publish chunk: 128 coalesced 16B coherent stores (2KB contiguous)
    if (tid < 128) {
      bf16* dst = hex_d + (size_t)(it & 1) * 32768 + (size_t)nb * 1024;
      storeb8_cc(dst + tid * 8, ((const bf16x8*)&stg[0][0][0])[tid]);
    }
    asm volatile("s_waitcnt vmcnt(0)" ::: "memory");
    __syncthreads();
    if (tid == 0)
      __hip_atomic_store(&flg[nb], (unsigned)(it + 1), __ATOMIC_RELAXED,
                         __HIP_MEMORY_SCOPE_AGENT);
  }
}

// ---------------------------------------------------------------------------
// Sentence-level GRU (21 steps), round-9 structure. x_proj precomputed f32
// (includes b_ih). Writes sent_out (f32) to d_out and final h to hfin.
__global__ __launch_bounds__(256) void gru_sent(
    const float* __restrict__ whhF, const float* __restrict__ whhB,
    const float* __restrict__ bhhF, const float* __restrict__ bhhB,
    const float* __restrict__ xproj,  // [2][672][1536] f32, row = t*32+b
    bf16* __restrict__ hexb,          // [2][2][32][2][32][16] bf16
    unsigned* __restrict__ flags,     // [2][32] u32 (zeroed, sent region)
    float* __restrict__ out,          // sent_out [32][21][1024] f32
    float* __restrict__ hfin)         // [2][32][512] f32
{
  __shared__ bf16 WlH[48][516];
  __shared__ bf16 WlL[48][516];
  __shared__ float red[2][3][64][4];
  __shared__ __align__(16) bf16 stg[2][32][16];
  const int tid = threadIdx.x;
  const int bx = blockIdx.x;
  const int dir = bx >> 5, nb = bx & 31;
  const int c0 = nb * 16;
  const float* whh = dir ? whhB : whhF;
  const float* bhh = dir ? bhhB : bhhF;
  unsigned* flg = flags + dir * 32;

#pragma unroll
  for (int i = 0; i < 24; ++i) {
    int c = tid + 256 * i;
    int r = c >> 7, kc = (c & 127) * 4;
    int gr = ((r >> 4) << 9) + c0 + (r & 15);
    float4 v = *(const float4*)(whh + (size_t)gr * 512 + kc);
    float vv[4] = {v.x, v.y, v.z, v.w};
#pragma unroll
    for (int j = 0; j < 4; ++j) {
      bf16 h = f2b(vv[j]);
      WlH[r][kc + j] = h;
      WlL[r][kc + j] = f2b(vv[j] - b2f(h));
    }
  }
  __syncthreads();

  const int wave = tid >> 6, lane = tid & 63;
  const int kh = wave >> 1;
  const int mh = wave & 1;
  const int m0 = mh * 16;
  const int l15 = lane & 15, lq = lane >> 4;
  const int colg = c0 + l15;
  const int rowq = m0 + lq * 4;
  const int arow = m0 + l15;
  const int nboff = lq >> 1;
  const int coff = (lq & 1) * 8;
  const float bhr = bhh[colg];
  const float bhz = bhh[512 + colg];
  const float bhn = bhh[1024 + colg];

  float hp_reg[4] = {0.f, 0.f, 0.f, 0.f};
  bf16* hex_d = hexb + (size_t)dir * 32768 * 2;

  for (int it = 0; it < 21; ++it) {
    const int t = dir ? (20 - it) : it;
    f32x4 accR = {}, accZ = {}, hN = {};

    if (it > 0) {
      if (tid < 32) {
        while (__hip_atomic_load(&flg[tid], __ATOMIC_RELAXED,
                                 __HIP_MEMORY_SCOPE_AGENT) < (unsigned)it)
          __builtin_amdgcn_s_sleep(1);
      }
      __syncthreads();

      const bf16* hb = hex_d + (size_t)((it - 1) & 1) * 32768;
      const int inrow = arow * 16 + coff;
      bf16x8 hiA[8], loA[8];
#pragma unroll
      for (int c = 0; c < 8; ++c) {
        const bf16* ph = hb + (size_t)(kh * 16 + c * 2 + nboff) * 1024 + inrow;
        hiA[c] = loadb8_cc(ph);
        loA[c] = loadb8_cc(ph + 512);
      }
      asm volatile("s_waitcnt vmcnt(0)" ::: "memory");
      __builtin_amdgcn_sched_barrier(0);

#pragma unroll
      for (int c = 0; c < 8; ++c) {
        const int kk = kh * 256 + c * 32 + lq * 8;
        bf16x8 wrh = *(const bf16x8*)&WlH[l15][kk];
        bf16x8 wrl = *(const bf16x8*)&WlL[l15][kk];
        bf16x8 wzh = *(const bf16x8*)&WlH[16 + l15][kk];
        bf16x8 wzl = *(const bf16x8*)&WlL[16 + l15][kk];
        bf16x8 wnh = *(const bf16x8*)&WlH[32 + l15][kk];
        bf16x8 wnl = *(const bf16x8*)&WlL[32 + l15][kk];
        accR = mfma16(hiA[c], wrh, accR);
        accR = mfma16(loA[c], wrh, accR);
        accR = mfma16(hiA[c], wrl, accR);
        accZ = mfma16(hiA[c], wzh, accZ);
        accZ = mfma16(loA[c], wzh, accZ);
        accZ = mfma16(hiA[c], wzl, accZ);
        hN = mfma16(hiA[c], wnh, hN);
        hN = mfma16(loA[c], wnh, hN);
        hN = mfma16(hiA[c], wnl, hN);
      }
    }

    if (kh == 0) {
      *(f32x4*)&red[mh][0][lane][0] = accR;
      *(f32x4*)&red[mh][1][lane][0] = accZ;
      *(f32x4*)&red[mh][2][lane][0] = hN;
    }
    __syncthreads();
    if (kh == 1) {
      accR = accR + *(const f32x4*)&red[mh][0][lane][0];
      accZ = accZ + *(const f32x4*)&red[mh][1][lane][0];
      hN = hN + *(const f32x4*)&red[mh][2][lane][0];

      const float* xp = xproj + ((size_t)dir * 672 + t * 32) * 1536;
#pragma unroll
      for (int r = 0; r < 4; ++r) {
        int b = rowq + r;
        float xr = xp[b * 1536 + colg];
        float xz = xp[b * 1536 + 512 + colg];
        float xn = xp[b * 1536 + 1024 + colg];
        float rr = 1.f / (1.f + expf(-(xr + accR[r] + bhr)));
        float zz = 1.f / (1.f + expf(-(xz + accZ[r] + bhz)));
        float nn = tanhf(xn + rr * (hN[r] + bhn));
        float h2 = (1.f - zz) * nn + zz * hp_reg[r];
        hp_reg[r] = h2;
        bf16 hi = f2b(h2);
        stg[0][b][l15] = hi;
        stg[1][b][l15] = f2b(h2 - b2f(hi));
        out[(size_t)b * (21 * 1024) + (size_t)t * 1024 + (dir << 9) + colg] = h2;
        if (it == 20) hfin[(dir << 14) + b * 512 + colg] = h2;
      }
    }

    __syncthreads();   // stg complete
    if (tid < 128) {
      bf16* dst = hex_d + (size_t)(it & 1) * 32768 + (size_t)nb * 1024;
      storeb8_cc(dst + tid * 8, ((const bf16x8*)&stg[0][0][0])[tid]);
    }
    asm volatile("s_waitcnt vmcnt(0)" ::: "memory");
    __syncthreads();
    if (tid == 0)
      __hip_atomic_store(&flg[nb], (unsigned)(it + 1), __ATOMIC_RELAXED,
                         __HIP_MEMORY_SCOPE_AGENT);
  }
}

// ---------------------------------------------------------------------------
// fc: hidden[b][j] = concat(hf,hb)[b] . fc_w[j] + fc_b[j]   (one block per b)
__global__ __launch_bounds__(256) void fc_k(const float* __restrict__ hfin,
                                            const float* __restrict__ fcw,
                                            const float* __restrict__ fcb,
                                            float* __restrict__ out) {
  __shared__ float hl[1024];
  int b = blockIdx.x, tid = threadIdx.x;
  for (int i = tid; i < 512; i += 256) {
    hl[i] = hfin[b * 512 + i];
    hl[512 + i] = hfin[16384 + b * 512 + i];
  }
  __syncthreads();
  for (int j = tid; j < 512; j += 256) {
    const float* wr = fcw + (size_t)j * 1024;
    float acc = 0.f;
    for (int k = 0; k < 1024; k += 4) {
      float4 wv = *(const float4*)(wr + k);
      acc += hl[k] * wv.x + hl[k + 1] * wv.y + hl[k + 2] * wv.z +
             hl[k + 3] * wv.w;
    }
    out[688128 + b * 512 + j] = acc + fcb[j];
  }
}

// ---------------------------------------------------------------------------
extern "C" void kernel_launch(void* const* d_in, const int* in_sizes, int n_in,
                              void* d_out, int out_size, void* d_ws,
                              size_t ws_size, hipStream_t stream) {
  const int* seq = (const int*)d_in[0];
  const float* emb = (const float*)d_in[1];
  const float* w_ih_wf = (const float*)d_in[2];
  const float* w_hh_wf = (const float*)d_in[3];
  const float* b_ih_wf = (const float*)d_in[4];
  const float* b_hh_wf = (const float*)d_in[5];
  const float* w_ih_wb = (const float*)d_in[6];
  const float* w_hh_wb = (const float*)d_in[7];
  const float* b_ih_wb = (const float*)d_in[8];
  const float* b_hh_wb = (const float*)d_in[9];
  const float* w_ih_sf = (const float*)d_in[10];
  const float* w_hh_sf = (const float*)d_in[11];
  const float* b_ih_sf = (const float*)d_in[12];
  const float* b_hh_sf = (const float*)d_in[13];
  const float* w_ih_sb = (const float*)d_in[14];
  const float* w_hh_sb = (const float*)d_in[15];
  const float* b_ih_sb = (const float*)d_in[16];
  const float* b_hh_sb = (const float*)d_in[17];
  const float* fc_w = (const float*)d_in[18];
  const float* fc_b = (const float*)d_in[19];

  char* ws = (char*)d_ws;
  bf16* xpad = (bf16*)(ws + 0);                // [12800][320]        8,192,000
  bf16* wpadw = (bf16*)(ws + 8192000);         // [2][1536][320]      1,966,080
  float* srep = (float*)(ws + 16449536);       // [672][1024] f32     2,752,512
  float* xps = (float*)(ws + 19202048);        // [2][672][1536] f32  8,257,536
  bf16* hexb = (bf16*)(ws + 27459584);         // [2][2][32][2][32][16] 262,144
  float* hfin = (float*)(ws + 27721728);       // [2][32][512] f32      131,072
  unsigned* flags = (unsigned*)(ws + 27852800);// [512] u32               2,048
  // total: 27,854,848 bytes

  // flags MUST be zeroed every call (replays do not re-poison ws); all other
  // intermediates are fully written before first read.
  hipMemsetAsync(flags, 0, 2048, stream);

  // stage bf16 conversions (word-level only; sentence W converts in-GEMM)
  pad_gather_cvt<<<3200, 256, 0, stream>>>(emb, xpad, seq, 12800);
  pad_gather_cvt<<<384, 256, 0, stream>>>(w_ih_wf, wpadw, nullptr, 1536);
  pad_gather_cvt<<<384, 256, 0, stream>>>(w_ih_wb, wpadw + 1536 * 320, nullptr,
                                          1536);

  {
    unsigned* flgW = flags;
    void* args[] = {(void*)&w_hh_wf, (void*)&w_hh_wb, (void*)&b_hh_wf,
                    (void*)&b_hh_wb, (void*)&b_ih_wf, (void*)&b_ih_wb,
                    (void*)&wpadw,   (void*)&xpad,    (void*)&hexb,
                    (void*)&flgW,    (void*)&srep};
    hipLaunchCooperativeKernel((const void*)gru_word, dim3(64), dim3(256),
                               args, 0, stream);
  }

  dim3 g2(12, 6, 2);
  gemm_bt_al2<<<g2, 256, 0, stream>>>(srep, w_ih_sf, w_ih_sb, b_ih_sf,
                                      b_ih_sb, xps, 672, 1536, 1024);

  {
    unsigned* flgS = flags + 128;
    float* outp = (float*)d_out;
    const float* xpsc = xps;
    void* args[] = {(void*)&w_hh_sf, (void*)&w_hh_sb, (void*)&b_hh_sf,
                    (void*)&b_hh_sb, (void*)&xpsc,    (void*)&hexb,
                    (void*)&flgS,    (void*)&outp,    (void*)&hfin};
    hipLaunchCooperativeKernel((const void*)gru_sent, dim3(64), dim3(256),
                               args, 0, stream);
  }

  fc_k<<<32, 256, 0, stream>>>(hfin, fc_w, fc_b, (float*)d_out);
}

// Round 12
// 2298.552 us; speedup vs baseline: 1.0872x; 1.0872x over previous
//
#include <hip/hip_runtime.h>
#include <hip/hip_bf16.h>
#include <hip/hip_cooperative_groups.h>

typedef __bf16 bf16;
typedef __bf16 bf16x4 __attribute__((ext_vector_type(4)));
typedef __bf16 bf16x8 __attribute__((ext_vector_type(8)));
typedef float f32x4 __attribute__((ext_vector_type(4)));

static __device__ __forceinline__ bf16 f2b(float x) { return (bf16)x; }
static __device__ __forceinline__ float b2f(bf16 x) { return (float)x; }

static __device__ __forceinline__ f32x4 mfma16(bf16x8 a, bf16x8 b, f32x4 c) {
  return __builtin_amdgcn_mfma_f32_16x16x32_bf16(a, b, c, 0, 0, 0);
}

// coherent (cross-XCD) 16B load: bypass L2 via sc0 sc1. Valid only after
// s_waitcnt vmcnt + sched_barrier(0).
static __device__ __forceinline__ bf16x8 loadb8_cc(const bf16* p) {
  bf16x8 v;
  asm volatile("global_load_dwordx4 %0, %1, off sc0 sc1" : "=v"(v) : "v"(p) : "memory");
  return v;
}
// coherent 16B store (write-through to coherence point)
static __device__ __forceinline__ void storeb8_cc(bf16* p, bf16x8 v) {
  asm volatile("global_store_dwordx4 %0, %1, off sc0 sc1" :: "v"(p), "v"(v) : "memory");
}

// ---------------------------------------------------------------------------
// pad_gather_cvt: dst row m = 320 bf16 (cols 300..319 zero) from f32 src row.
// If seq != null: src row = seq[b*400+s] with (s=m/32, b=m%32), else row m.
__global__ __launch_bounds__(256) void pad_gather_cvt(
    const float* __restrict__ src, bf16* __restrict__ dst,
    const int* __restrict__ seq, int nrows) {
  int row = blockIdx.x * 4 + (threadIdx.x >> 6);
  int lane = threadIdx.x & 63;
  if (row >= nrows) return;
  int srow;
  if (seq) {
    int s = row >> 5, b = row & 31;
    srow = seq[b * 400 + s];
  } else {
    srow = row;
  }
  const float* sp = src + (size_t)srow * 300;
  bf16* dp = dst + (size_t)row * 320;
  for (int i = lane; i < 320; i += 64) dp[i] = (i < 300) ? f2b(sp[i]) : (bf16)0.f;
}

// ---------------------------------------------------------------------------
// gemm_bt_al2: C[z][M][N] = A[M][K] * W_z[N][K]^T + bias_z, A f32 (hi/lo
// split -> f32-faithful), W f32 converted to bf16 in-kernel (bit-identical
// to the old pre-conversion), C f32. z = blockIdx.z picks direction.
__global__ __launch_bounds__(256) void gemm_bt_al2(
    const float* __restrict__ A, const float* __restrict__ WF,
    const float* __restrict__ WB, const float* __restrict__ biasF,
    const float* __restrict__ biasB, float* __restrict__ C,
    int M, int N, int K) {
  __shared__ bf16 AsH[128][72];
  __shared__ bf16 AsL[128][72];
  __shared__ bf16 Ws[128][72];
  const int z = blockIdx.z;
  const float* W = z ? WB : WF;
  const float* bias = z ? biasB : biasF;
  float* Cz = C + (size_t)z * M * N;
  const int n0 = blockIdx.x * 128, m0 = blockIdx.y * 128;
  const int tid = threadIdx.x;
  const int wave = tid >> 6, lane = tid & 63;
  const int l15 = lane & 15, lq = lane >> 4;
  const int wm = (wave >> 1) * 64, wn = (wave & 1) * 64;

  f32x4 acc[4][4] = {};

  for (int k0 = 0; k0 < K; k0 += 64) {
    __syncthreads();
#pragma unroll
    for (int i = 0; i < 8; ++i) {      // A: 128x64 f32, hi/lo split
      int c = tid + 256 * i;
      int r = c >> 4, cc = (c & 15) * 4;
      int gr = m0 + r;
      float4 v = {0.f, 0.f, 0.f, 0.f};
      if (gr < M) v = *(const float4*)(A + (size_t)gr * K + k0 + cc);
      float vv[4] = {v.x, v.y, v.z, v.w};
#pragma unroll
      for (int j = 0; j < 4; ++j) {
        bf16 h = f2b(vv[j]);
        AsH[r][cc + j] = h;
        AsL[r][cc + j] = f2b(vv[j] - b2f(h));
      }
    }
#pragma unroll
    for (int i = 0; i < 8; ++i) {      // W: 128x64 f32 -> bf16 hi
      int c = tid + 256 * i;
      int r = c >> 4, cc = (c & 15) * 4;
      float4 v = *(const float4*)(W + (size_t)(n0 + r) * K + k0 + cc);
      Ws[r][cc + 0] = f2b(v.x);
      Ws[r][cc + 1] = f2b(v.y);
      Ws[r][cc + 2] = f2b(v.z);
      Ws[r][cc + 3] = f2b(v.w);
    }
    __syncthreads();
#pragma unroll
    for (int ks = 0; ks < 64; ks += 32) {
      bf16x8 afH[4], afL[4], bfr[4];
#pragma unroll
      for (int i = 0; i < 4; ++i) {
        afH[i] = *(const bf16x8*)&AsH[wm + i * 16 + l15][ks + lq * 8];
        afL[i] = *(const bf16x8*)&AsL[wm + i * 16 + l15][ks + lq * 8];
      }
#pragma unroll
      for (int j = 0; j < 4; ++j)
        bfr[j] = *(const bf16x8*)&Ws[wn + j * 16 + l15][ks + lq * 8];
#pragma unroll
      for (int i = 0; i < 4; ++i)
#pragma unroll
        for (int j = 0; j < 4; ++j) {
          acc[i][j] = mfma16(afH[i], bfr[j], acc[i][j]);
          acc[i][j] = mfma16(afL[i], bfr[j], acc[i][j]);
        }
    }
  }

#pragma unroll
  for (int i = 0; i < 4; ++i)
#pragma unroll
    for (int j = 0; j < 4; ++j) {
      int col = n0 + wn + j * 16 + l15;
      float bv = bias[col];
#pragma unroll
      for (int r = 0; r < 4; ++r) {
        int row = m0 + wm + i * 16 + lq * 4 + r;
        if (row < M) Cz[(size_t)row * N + col] = acc[i][j][r] + bv;
      }
    }
}

// ---------------------------------------------------------------------------
// Word-level GRU, fenceless producer-consumer, round-9 verified schedule:
// x-projection BEFORE the poll (hidden under the straggler wait window),
// then poll -> barrier -> h cc-loads -> vmcnt(0) -> h MFMAs -> reduce ->
// epilogue -> 128-thread coalesced publish -> vmcnt(0) -> barrier -> flag.
// 64 blocks x 256 threads: dir=bx>>5, nb=bx&31 owns 16 h-cols. kh=wave>>1
// splits K, mh=wave&1 picks batch tile; kh==1 does reduce + epilogue.
// hexb: [dir][parity][nb][plane(hi/lo)][32 rows][16 cols] bf16.
__global__ __launch_bounds__(256) void gru_word(
    const float* __restrict__ whhF, const float* __restrict__ whhB,
    const float* __restrict__ bhhF, const float* __restrict__ bhhB,
    const float* __restrict__ bihF, const float* __restrict__ bihB,
    const bf16* __restrict__ wpad,   // [2][1536][320] bf16 (padded w_ih)
    const bf16* __restrict__ xpad,   // [400*32][320] bf16 (padded emb gather)
    bf16* __restrict__ hexb,         // [2][2][32][2][32][16] bf16
    unsigned* __restrict__ flags,    // [2][32] u32 (zeroed)
    float* __restrict__ srep)        // [672][1024] f32
{
  __shared__ bf16 WlH[48][516];
  __shared__ bf16 WlL[48][516];
  __shared__ bf16 Xw[48][324];
  __shared__ float red[2][4][64][4];
  __shared__ __align__(16) bf16 stg[2][32][16];  // [plane][row][relcol]
  const int tid = threadIdx.x;
  const int bx = blockIdx.x;
  const int dir = bx >> 5, nb = bx & 31;
  const int c0 = nb * 16;
  const float* whh = dir ? whhB : whhF;
  const float* bhh = dir ? bhhB : bhhF;
  const float* bih = dir ? bihB : bihF;
  const bf16* wih = wpad + (size_t)dir * 1536 * 320;
  unsigned* flg = flags + dir * 32;

  // stage w_hh slice with hi/lo split: LDS row r=g*16+rc <-> w_hh[g*512+c0+rc]
#pragma unroll
  for (int i = 0; i < 24; ++i) {
    int c = tid + 256 * i;
    int r = c >> 7, kc = (c & 127) * 4;
    int gr = ((r >> 4) << 9) + c0 + (r & 15);
    float4 v = *(const float4*)(whh + (size_t)gr * 512 + kc);
    float vv[4] = {v.x, v.y, v.z, v.w};
#pragma unroll
    for (int j = 0; j < 4; ++j) {
      bf16 h = f2b(vv[j]);
      WlH[r][kc + j] = h;
      WlL[r][kc + j] = f2b(vv[j] - b2f(h));
    }
  }
#pragma unroll
  for (int i = 0; i < 8; ++i) {
    int c = tid + 256 * i;
    if (c < 1920) {
      int r = c / 40, ch = (c % 40) * 8;
      int gr = ((r >> 4) << 9) + c0 + (r & 15);
      *(bf16x8*)&Xw[r][ch] = *(const bf16x8*)(wih + (size_t)gr * 320 + ch);
    }
  }
  __syncthreads();

  const int wave = tid >> 6, lane = tid & 63;
  const int kh = wave >> 1;            // K half
  const int mh = wave & 1;             // batch tile
  const int m0 = mh * 16;
  const int l15 = lane & 15, lq = lane >> 4;
  const int colg = c0 + l15;
  const int rowq = m0 + lq * 4;
  const int arow = m0 + l15;           // A-fragment batch row
  const int nboff = lq >> 1;           // chunk-owner offset within 32-K slab
  const int coff = (lq & 1) * 8;       // col offset within chunk row
  const int kb = kh * 160;             // x K-range base for this wave
  const float bhr = bhh[colg];
  const float bhz = bhh[512 + colg];
  const float bhn = bhh[1024 + colg];
  const float bir = bih[colg];
  const float biz = bih[512 + colg];
  const float bin_ = bih[1024 + colg];

  float pacc0 = 0.f, pacc1 = 0.f, pacc2 = 0.f, pacc3 = 0.f;
  float hp_reg[4] = {0.f, 0.f, 0.f, 0.f};   // own h_prev in registers (kh==1)
  bf16* hex_d = hexb + (size_t)dir * 32768 * 2;

  for (int it = 0; it < 400; ++it) {
    const int t = dir ? (399 - it) : it;
    f32x4 accR = {}, accZ = {}, xN = {}, hN = {};

    // x-projection FIRST (h-independent): runs inside the straggler window
    // while other blocks finish publishing step it-1. K split across kh.
    {
      const bf16* xrow = xpad + (size_t)(t * 32 + arow) * 320;
#pragma unroll
      for (int k0 = 0; k0 < 160; k0 += 32) {
        const int kk = kb + k0 + lq * 8;
        bf16x8 a = *(const bf16x8*)(xrow + kk);
        accR = mfma16(a, *(const bf16x8*)&Xw[l15][kk], accR);
        accZ = mfma16(a, *(const bf16x8*)&Xw[16 + l15][kk], accZ);
        xN = mfma16(a, *(const bf16x8*)&Xw[32 + l15][kk], xN);
      }
    }

    if (it > 0) {
      // wait for all 32 producer blocks of this direction at step it-1
      if (tid < 32) {
        while (__hip_atomic_load(&flg[tid], __ATOMIC_RELAXED,
                                 __HIP_MEMORY_SCOPE_AGENT) < (unsigned)it)
          __builtin_amdgcn_s_sleep(1);
      }
      __syncthreads();

      // issue coherent h loads from block-major chunks, one wait.
      // k element = kh*256 + c*32 + lq*8 + j -> owner chunk nb' = k/16 =
      // kh*16 + c*2 + (lq>>1), within-chunk col = (lq&1)*8 + j.
      const bf16* hb = hex_d + (size_t)((it - 1) & 1) * 32768;
      const int inrow = arow * 16 + coff;
      bf16x8 hiA[8], loA[8];
#pragma unroll
      for (int c = 0; c < 8; ++c) {
        const bf16* ph = hb + (size_t)(kh * 16 + c * 2 + nboff) * 1024 + inrow;
        hiA[c] = loadb8_cc(ph);
        loA[c] = loadb8_cc(ph + 512);
      }
      asm volatile("s_waitcnt vmcnt(0)" ::: "memory");
      __builtin_amdgcn_sched_barrier(0);

#pragma unroll
      for (int c = 0; c < 8; ++c) {
        const int kk = kh * 256 + c * 32 + lq * 8;
        bf16x8 wrh = *(const bf16x8*)&WlH[l15][kk];
        bf16x8 wrl = *(const bf16x8*)&WlL[l15][kk];
        bf16x8 wzh = *(const bf16x8*)&WlH[16 + l15][kk];
        bf16x8 wzl = *(const bf16x8*)&WlL[16 + l15][kk];
        bf16x8 wnh = *(const bf16x8*)&WlH[32 + l15][kk];
        bf16x8 wnl = *(const bf16x8*)&WlL[32 + l15][kk];
        accR = mfma16(hiA[c], wrh, accR);
        accR = mfma16(loA[c], wrh, accR);
        accR = mfma16(hiA[c], wrl, accR);
        accZ = mfma16(hiA[c], wzh, accZ);
        accZ = mfma16(loA[c], wzh, accZ);
        accZ = mfma16(hiA[c], wzl, accZ);
        hN = mfma16(hiA[c], wnh, hN);
        hN = mfma16(loA[c], wnh, hN);
        hN = mfma16(hiA[c], wnl, hN);
      }
    }

    // cross-wave K reduction
    if (kh == 0) {
      *(f32x4*)&red[mh][0][lane][0] = accR;
      *(f32x4*)&red[mh][1][lane][0] = accZ;
      *(f32x4*)&red[mh][2][lane][0] = xN;
      *(f32x4*)&red[mh][3][lane][0] = hN;
    }
    __syncthreads();
    if (kh == 1) {
      accR = accR + *(const f32x4*)&red[mh][0][lane][0];
      accZ = accZ + *(const f32x4*)&red[mh][1][lane][0];
      xN = xN + *(const f32x4*)&red[mh][2][lane][0];
      hN = hN + *(const f32x4*)&red[mh][3][lane][0];

      float h2v[4];
#pragma unroll
      for (int r = 0; r < 4; ++r) {
        int b = rowq + r;
        float rr = 1.f / (1.f + expf(-(accR[r] + bir + bhr)));
        float zz = 1.f / (1.f + expf(-(accZ[r] + biz + bhz)));
        float nn = tanhf(xN[r] + bin_ + rr * (hN[r] + bhn));
        h2v[r] = (1.f - zz) * nn + zz * hp_reg[r];
        hp_reg[r] = h2v[r];
        bf16 hi = f2b(h2v[r]);
        stg[0][b][l15] = hi;
        stg[1][b][l15] = f2b(h2v[r] - b2f(hi));
      }

      // segment mean pooling (f32)
      int sg = (t == 0) ? 0 : ((t + 19) / 20);
      if (sg > 20) sg = 20;
      float ic = (sg == 0) ? 1.0f : (sg == 20 ? (1.0f / 19.0f) : 0.05f);
      pacc0 += h2v[0] * ic; pacc1 += h2v[1] * ic;
      pacc2 += h2v[2] * ic; pacc3 += h2v[3] * ic;
      bool flush = dir ? (t == 0 || (t % 20) == 1) : ((t % 20) == 0 || t == 399);
      if (flush) {
        float* sp = srep + ((size_t)(sg * 32 + rowq) * 1024) + (dir << 9) + colg;
        sp[0] = pacc0; sp[1024] = pacc1;
        sp[2048] = pacc2; sp[3072] = pacc3;
        pacc0 = pacc1 = pacc2 = pacc3 = 0.f;
      }
    }

    __syncthreads();   // stg complete
    // publish chunk: 128 coalesced 16B coherent stores (2KB contiguous)
    if (tid < 128) {
      bf16* dst = hex_d + (size_t)(it & 1) * 32768 + (size_t)nb * 1024;
      storeb8_cc(dst + tid * 8, ((const bf16x8*)&stg[0][0][0])[tid]);
    }
    asm volatile("s_waitcnt vmcnt(0)" ::: "memory");
    __syncthreads();
    if (tid == 0)
      __hip_atomic_store(&flg[nb], (unsigned)(it + 1), __ATOMIC_RELAXED,
                         __HIP_MEMORY_SCOPE_AGENT);
  }
}

// ---------------------------------------------------------------------------
// Sentence-level GRU (21 steps), round-9 structure. x_proj precomputed f32
// (includes b_ih). Writes sent_out (f32) to d_out and final h to hfin.
__global__ __launch_bounds__(256) void gru_sent(
    const float* __restrict__ whhF, const float* __restrict__ whhB,
    const float* __restrict__ bhhF, const float* __restrict__ bhhB,
    const float* __restrict__ xproj,  // [2][672][1536] f32, row = t*32+b
    bf16* __restrict__ hexb,          // [2][2][32][2][32][16] bf16
    unsigned* __restrict__ flags,     // [2][32] u32 (zeroed, sent region)
    float* __restrict__ out,          // sent_out [32][21][1024] f32
    float* __restrict__ hfin)         // [2][32][512] f32
{
  __shared__ bf16 WlH[48][516];
  __shared__ bf16 WlL[48][516];
  __shared__ float red[2][3][64][4];
  __shared__ __align__(16) bf16 stg[2][32][16];
  const int tid = threadIdx.x;
  const int bx = blockIdx.x;
  const int dir = bx >> 5, nb = bx & 31;
  const int c0 = nb * 16;
  const float* whh = dir ? whhB : whhF;
  const float* bhh = dir ? bhhB : bhhF;
  unsigned* flg = flags + dir * 32;

#pragma unroll
  for (int i = 0; i < 24; ++i) {
    int c = tid + 256 * i;
    int r = c >> 7, kc = (c & 127) * 4;
    int gr = ((r >> 4) << 9) + c0 + (r & 15);
    float4 v = *(const float4*)(whh + (size_t)gr * 512 + kc);
    float vv[4] = {v.x, v.y, v.z, v.w};
#pragma unroll
    for (int j = 0; j < 4; ++j) {
      bf16 h = f2b(vv[j]);
      WlH[r][kc + j] = h;
      WlL[r][kc + j] = f2b(vv[j] - b2f(h));
    }
  }
  __syncthreads();

  const int wave = tid >> 6, lane = tid & 63;
  const int kh = wave >> 1;
  const int mh = wave & 1;
  const int m0 = mh * 16;
  const int l15 = lane & 15, lq = lane >> 4;
  const int colg = c0 + l15;
  const int rowq = m0 + lq * 4;
  const int arow = m0 + l15;
  const int nboff = lq >> 1;
  const int coff = (lq & 1) * 8;
  const float bhr = bhh[colg];
  const float bhz = bhh[512 + colg];
  const float bhn = bhh[1024 + colg];

  float hp_reg[4] = {0.f, 0.f, 0.f, 0.f};
  bf16* hex_d = hexb + (size_t)dir * 32768 * 2;

  for (int it = 0; it < 21; ++it) {
    const int t = dir ? (20 - it) : it;
    f32x4 accR = {}, accZ = {}, hN = {};

    if (it > 0) {
      if (tid < 32) {
        while (__hip_atomic_load(&flg[tid], __ATOMIC_RELAXED,
                                 __HIP_MEMORY_SCOPE_AGENT) < (unsigned)it)
          __builtin_amdgcn_s_sleep(1);
      }
      __syncthreads();

      const bf16* hb = hex_d + (size_t)((it - 1) & 1) * 32768;
      const int inrow = arow * 16 + coff;
      bf16x8 hiA[8], loA[8];
#pragma unroll
      for (int c = 0; c < 8; ++c) {
        const bf16* ph = hb + (size_t)(kh * 16 + c * 2 + nboff) * 1024 + inrow;
        hiA[c] = loadb8_cc(ph);
        loA[c] = loadb8_cc(ph + 512);
      }
      asm volatile("s_waitcnt vmcnt(0)" ::: "memory");
      __builtin_amdgcn_sched_barrier(0);

#pragma unroll
      for (int c = 0; c < 8; ++c) {
        const int kk = kh * 256 + c * 32 + lq * 8;
        bf16x8 wrh = *(const bf16x8*)&WlH[l15][kk];
        bf16x8 wrl = *(const bf16x8*)&WlL[l15][kk];
        bf16x8 wzh = *(const bf16x8*)&WlH[16 + l15][kk];
        bf16x8 wzl = *(const bf16x8*)&WlL[16 + l15][kk];
        bf16x8 wnh = *(const bf16x8*)&WlH[32 + l15][kk];
        bf16x8 wnl = *(const bf16x8*)&WlL[32 + l15][kk];
        accR = mfma16(hiA[c], wrh, accR);
        accR = mfma16(loA[c], wrh, accR);
        accR = mfma16(hiA[c], wrl, accR);
        accZ = mfma16(hiA[c], wzh, accZ);
        accZ = mfma16(loA[c], wzh, accZ);
        accZ = mfma16(hiA[c], wzl, accZ);
        hN = mfma16(hiA[c], wnh, hN);
        hN = mfma16(loA[c], wnh, hN);
        hN = mfma16(hiA[c], wnl, hN);
      }
    }

    if (kh == 0) {
      *(f32x4*)&red[mh][0][lane][0] = accR;
      *(f32x4*)&red[mh][1][lane][0] = accZ;
      *(f32x4*)&red[mh][2][lane][0] = hN;
    }
    __syncthreads();
    if (kh == 1) {
      accR = accR + *(const f32x4*)&red[mh][0][lane][0];
      accZ = accZ + *(const f32x4*)&red[mh][1][lane][0];
      hN = hN + *(const f32x4*)&red[mh][2][lane][0];

      const float* xp = xproj + ((size_t)dir * 672 + t * 32) * 1536;
#pragma unroll
      for (int r = 0; r < 4; ++r) {
        int b = rowq + r;
        float xr = xp[b * 1536 + colg];
        float xz = xp[b * 1536 + 512 + colg];
        float xn = xp[b * 1536 + 1024 + colg];
        float rr = 1.f / (1.f + expf(-(xr + accR[r] + bhr)));
        float zz = 1.f / (1.f + expf(-(xz + accZ[r] + bhz)));
        float nn = tanhf(xn + rr * (hN[r] + bhn));
        float h2 = (1.f - zz) * nn + zz * hp_reg[r];
        hp_reg[r] = h2;
        bf16 hi = f2b(h2);
        stg[0][b][l15] = hi;
        stg[1][b][l15] = f2b(h2 - b2f(hi));
        out[(size_t)b * (21 * 1024) + (size_t)t * 1024 + (dir << 9) + colg] = h2;
        if (it == 20) hfin[(dir << 14) + b * 512 + colg] = h2;
      }
    }

    __syncthreads();   // stg complete
    if (tid < 128) {
      bf16* dst = hex_d + (size_t)(it & 1) * 32768 + (size_t)nb * 1024;
      storeb8_cc(dst + tid * 8, ((const bf16x8*)&stg[0][0][0])[tid]);
    }
    asm volatile("s_waitcnt vmcnt(0)" ::: "memory");
    __syncthreads();
    if (tid == 0)
      __hip_atomic_store(&flg[nb], (unsigned)(it + 1), __ATOMIC_RELAXED,
                         __HIP_MEMORY_SCOPE_AGENT);
  }
}

// ---------------------------------------------------------------------------
// fc: hidden[b][j] = concat(hf,hb)[b] . fc_w[j] + fc_b[j]   (one block per b)
__global__ __launch_bounds__(256) void fc_k(const float* __restrict__ hfin,
                                            const float* __restrict__ fcw,
                                            const float* __restrict__ fcb,
                                            float* __restrict__ out) {
  __shared__ float hl[1024];
  int b = blockIdx.x, tid = threadIdx.x;
  for (int i = tid; i < 512; i += 256) {
    hl[i] = hfin[b * 512 + i];
    hl[512 + i] = hfin[16384 + b * 512 + i];
  }
  __syncthreads();
  for (int j = tid; j < 512; j += 256) {
    const float* wr = fcw + (size_t)j * 1024;
    float acc = 0.f;
    for (int k = 0; k < 1024; k += 4) {
      float4 wv = *(const float4*)(wr + k);
      acc += hl[k] * wv.x + hl[k + 1] * wv.y + hl[k + 2] * wv.z +
             hl[k + 3] * wv.w;
    }
    out[688128 + b * 512 + j] = acc + fcb[j];
  }
}

// ---------------------------------------------------------------------------
extern "C" void kernel_launch(void* const* d_in, const int* in_sizes, int n_in,
                              void* d_out, int out_size, void* d_ws,
                              size_t ws_size, hipStream_t stream) {
  const int* seq = (const int*)d_in[0];
  const float* emb = (const float*)d_in[1];
  const float* w_ih_wf = (const float*)d_in[2];
  const float* w_hh_wf = (const float*)d_in[3];
  const float* b_ih_wf = (const float*)d_in[4];
  const float* b_hh_wf = (const float*)d_in[5];
  const float* w_ih_wb = (const float*)d_in[6];
  const float* w_hh_wb = (const float*)d_in[7];
  const float* b_ih_wb = (const float*)d_in[8];
  const float* b_hh_wb = (const float*)d_in[9];
  const float* w_ih_sf = (const float*)d_in[10];
  const float* w_hh_sf = (const float*)d_in[11];
  const float* b_ih_sf = (const float*)d_in[12];
  const float* b_hh_sf = (const float*)d_in[13];
  const float* w_ih_sb = (const float*)d_in[14];
  const float* w_hh_sb = (const float*)d_in[15];
  const float* b_ih_sb = (const float*)d_in[16];
  const float* b_hh_sb = (const float*)d_in[17];
  const float* fc_w = (const float*)d_in[18];
  const float* fc_b = (const float*)d_in[19];

  char* ws = (char*)d_ws;
  bf16* xpad = (bf16*)(ws + 0);                // [12800][320]        8,192,000
  bf16* wpadw = (bf16*)(ws + 8192000);         // [2][1536][320]      1,966,080
  float* srep = (float*)(ws + 16449536);       // [672][1024] f32     2,752,512
  float* xps = (float*)(ws + 19202048);        // [2][672][1536] f32  8,257,536
  bf16* hexb = (bf16*)(ws + 27459584);         // [2][2][32][2][32][16] 262,144
  float* hfin = (float*)(ws + 27721728);       // [2][32][512] f32      131,072
  unsigned* flags = (unsigned*)(ws + 27852800);// [512] u32               2,048
  // total: 27,854,848 bytes

  // flags MUST be zeroed every call (replays do not re-poison ws); all other
  // intermediates are fully written before first read.
  hipMemsetAsync(flags, 0, 2048, stream);

  // stage bf16 conversions (word-level only; sentence W converts in-GEMM)
  pad_gather_cvt<<<3200, 256, 0, stream>>>(emb, xpad, seq, 12800);
  pad_gather_cvt<<<384, 256, 0, stream>>>(w_ih_wf, wpadw, nullptr, 1536);
  pad_gather_cvt<<<384, 256, 0, stream>>>(w_ih_wb, wpadw + 1536 * 320, nullptr,
                                          1536);

  {
    unsigned* flgW = flags;
    void* args[] = {(void*)&w_hh_wf, (void*)&w_hh_wb, (void*)&b_hh_wf,
                    (void*)&b_hh_wb, (void*)&b_ih_wf, (void*)&b_ih_wb,
                    (void*)&wpadw,   (void*)&xpad,    (void*)&hexb,
                    (void*)&flgW,    (void*)&srep};
    hipLaunchCooperativeKernel((const void*)gru_word, dim3(64), dim3(256),
                               args, 0, stream);
  }

  dim3 g2(12, 6, 2);
  gemm_bt_al2<<<g2, 256, 0, stream>>>(srep, w_ih_sf, w_ih_sb, b_ih_sf,
                                      b_ih_sb, xps, 672, 1536, 1024);

  {
    unsigned* flgS = flags + 128;
    float* outp = (float*)d_out;
    const float* xpsc = xps;
    void* args[] = {(void*)&w_hh_sf, (void*)&w_hh_sb, (void*)&b_hh_sf,
                    (void*)&b_hh_sb, (void*)&xpsc,    (void*)&hexb,
                    (void*)&flgS,    (void*)&outp,    (void*)&hfin};
    hipLaunchCooperativeKernel((const void*)gru_sent, dim3(64), dim3(256),
                               args, 0, stream);
  }

  fc_k<<<32, 256, 0, stream>>>(hfin, fc_w, fc_b, (float*)d_out);
}